// Round 7
// baseline (222.544 us; speedup 1.0000x reference)
//
#include <hip/hip_runtime.h>
#include <cmath>

typedef unsigned int uint;
typedef unsigned long long ull;

#define BATCH 32
#define NA 8400
#define NC 80
#define MAXDET 100
#define NMSTHR 0.65f
#define SCTHR 0.01f
#define NEG_INF (-INFINITY)

#define NT 1024         // NMS threads per block
#define NW (NT / 64)
#define EPT 9           // ceil(NA / NT)
#define NBINS 4096      // histogram bins on key[31:20]
#define CAP 512         // max candidates per sorted window

__device__ __forceinline__ float stable_sigmoid(float x) {
    if (x >= 0.f) return 1.f / (1.f + expf(-x));
    float e = expf(x);
    return e / (1.f + e);
}

// ---------------- decode: one thread per anchor ----------------
// Emits box, label, sort-key; accumulates per-image histogram (global
// atomics) and per-image max|coord| (segmented wave reduce -> <=2 atomics).
template<int HW, int W, int S>
__device__ __forceinline__ void decode_one(
    const float* __restrict__ cls, const float* __restrict__ reg,
    const float* __restrict__ obj, int b, int p,
    float4* box, float* score, int* lab_out)
{
    const float* cbase = cls + (size_t)b * NC * HW + p;

    float mq[4]; int lq[4];
    #pragma unroll
    for (int q = 0; q < 4; ++q) { mq[q] = NEG_INF; lq[q] = 0; }
    #pragma unroll
    for (int q = 0; q < 4; ++q) {
        #pragma unroll
        for (int c2 = 0; c2 < 20; ++c2) {
            int c = q * 20 + c2;
            float v = cbase[(size_t)c * HW];
            if (v > mq[q]) { mq[q] = v; lq[q] = c; }
        }
    }
    float maxv = mq[0]; int lab = lq[0];
    #pragma unroll
    for (int q = 1; q < 4; ++q)
        if (mq[q] > maxv) { maxv = mq[q]; lab = lq[q]; }

    const float* rb = reg + (size_t)b * 4 * HW + p;
    float r0 = rb[0];
    float r1 = rb[HW];
    float r2 = rb[2 * (size_t)HW];
    float r3 = rb[3 * (size_t)HW];
    float ov = obj[(size_t)b * HW + p];

    int y = p / W;
    int x = p - y * W;
    float sc = stable_sigmoid(maxv) * stable_sigmoid(ov);
    float cx = r0 * (float)S + (float)x * (float)S;
    float cy = r1 * (float)S + (float)y * (float)S;
    float bw = expf(r2) * (float)S;
    float bh = expf(r3) * (float)S;

    *box = make_float4(cx - bw * 0.5f, cy - bh * 0.5f,
                       cx + bw * 0.5f, cy + bh * 0.5f);
    *score = sc;
    *lab_out = lab;
}

__global__ __launch_bounds__(256) void decode_kernel(
    const float* __restrict__ cls0, const float* __restrict__ reg0, const float* __restrict__ obj0,
    const float* __restrict__ cls1, const float* __restrict__ reg1, const float* __restrict__ obj1,
    const float* __restrict__ cls2, const float* __restrict__ reg2, const float* __restrict__ obj2,
    float4* __restrict__ wboxes, int* __restrict__ wlabels, uint* __restrict__ wkeys,
    uint* __restrict__ whist, uint* __restrict__ wmaxabs)
{
    int gid = blockIdx.x * blockDim.x + threadIdx.x;   // grid == BATCH*NA exactly
    int b = gid / NA;
    int j = gid - b * NA;
    int lane = threadIdx.x & 63;

    float4 box; float score; int lab;
    if (j < 6400)
        decode_one<6400, 80, 8>(cls0, reg0, obj0, b, j, &box, &score, &lab);
    else if (j < 8000)
        decode_one<1600, 40, 16>(cls1, reg1, obj1, b, j - 6400, &box, &score, &lab);
    else
        decode_one<400, 20, 32>(cls2, reg2, obj2, b, j - 8000, &box, &score, &lab);

    wboxes[gid]  = box;
    wlabels[gid] = lab;
    uint key = (score >= SCTHR) ? ~__float_as_uint(score) : 0xFFFFFFFFu;
    wkeys[gid] = key;
    if (key != 0xFFFFFFFFu) atomicAdd(&whist[(size_t)b * NBINS + (key >> 20)], 1u);

    // per-image max|coord|: a wave spans at most 2 images (NA=8400 > 64)
    float m = fmaxf(fmaxf(fabsf(box.x), fabsf(box.y)),
                    fmaxf(fabsf(box.z), fabsf(box.w)));
    int b0 = __shfl(b, 0);
    float mh = (b == b0) ? m : 0.f;    // first-image part
    float ml = (b == b0) ? 0.f : m;    // second-image part (if any)
    #pragma unroll
    for (int o = 32; o >= 1; o >>= 1) {
        mh = fmaxf(mh, __shfl_xor(mh, o));
        ml = fmaxf(ml, __shfl_xor(ml, o));
    }
    if (lane == 0) atomicMax(&wmaxabs[b0], __float_as_uint(mh));
    int b63 = __shfl(b, 63);
    if (lane == 63 && b63 != b0) atomicMax(&wmaxabs[b63], __float_as_uint(ml));
}

// ---------------- NMS via sorted walk (exact greedy-NMS equivalence) ----------------
__global__ __launch_bounds__(NT) void nms_kernel(
    const float4* __restrict__ wboxes, const int* __restrict__ wlabels,
    const uint* __restrict__ wkeys, const uint* __restrict__ whist,
    const uint* __restrict__ wmaxabs, float* __restrict__ out)
{
    int b = blockIdx.x;
    int t = threadIdx.x;
    int lane = t & 63;
    int wv = t >> 6;
    const float4* boxes  = wboxes  + (size_t)b * NA;
    const int*    labels = wlabels + (size_t)b * NA;
    const uint*   keys   = wkeys   + (size_t)b * NA;

    __shared__ uint  s_cum[NBINS + 1];    // exclusive prefix
    __shared__ uint  s_wsum[NW];
    __shared__ ull   s_skey[CAP];
    __shared__ float s_kbox[MAXDET][4];   // kept OFFSET boxes
    __shared__ float s_ka1[MAXDET];
    __shared__ int   s_kidx[MAXDET];
    __shared__ float s_kscr[MAXDET];
    __shared__ int   s_klab[MAXDET];
    __shared__ int   s_kept, s_winlo, s_winhi, s_nsel;

    float off = __uint_as_float(wmaxabs[b]) + 1.f;   // broadcast scalar-ish load

    // ---- exclusive scan over 4096 hist bins: 4 bins/thread + shfl scans ----
    uint4 h = ((const uint4*)(whist + (size_t)b * NBINS))[t];
    uint l0 = h.x, l1 = h.y, l2 = h.z, l3 = h.w;
    uint L = l0 + l1 + l2 + l3;
    uint ls = L;
    #pragma unroll
    for (int o = 1; o < 64; o <<= 1) {
        uint v = __shfl_up(ls, o);
        if (lane >= o) ls += v;
    }
    if (lane == 63) s_wsum[wv] = ls;
    if (t == 0) { s_kept = 0; s_winlo = 0; }
    __syncthreads();
    if (t < NW) {
        uint v = s_wsum[t];
        uint vs = v;
        #pragma unroll
        for (int o = 1; o < NW; o <<= 1) {
            uint u = __shfl_up(vs, o);
            if ((t & 63) >= o) vs += u;
        }
        s_wsum[t] = vs - v;
    }
    __syncthreads();
    uint base = s_wsum[wv] + (ls - L);
    s_cum[4 * t]     = base;
    s_cum[4 * t + 1] = base + l0;
    s_cum[4 * t + 2] = base + l0 + l1;
    s_cum[4 * t + 3] = base + l0 + l1 + l2;
    if (t == NT - 1) s_cum[NBINS] = base + L;

    // ---- window loop (typically runs once) ----
    for (;;) {
        __syncthreads();
        int kept = s_kept, winlo = s_winlo;
        uint remaining = s_cum[NBINS] - s_cum[winlo];
        if (kept >= MAXDET || winlo >= NBINS || remaining == 0u) break;
        if (t == 0) { s_winhi = winlo + 1; s_nsel = 0; }   // giant-bin clamp floor
        if (t < CAP) s_skey[t] = ~0ull;
        __syncthreads();
        // parallel winhi: predicate monotone in i -> atomicMax over qualifying i+1
        uint cl = s_cum[winlo];
        #pragma unroll
        for (int q = 0; q < 4; ++q) {
            int i = t + q * NT;
            if (i >= winlo && i < NBINS && (s_cum[i + 1] - cl) <= (uint)CAP)
                atomicMax(&s_winhi, i + 1);
        }
        __syncthreads();
        int winhi = s_winhi;

        // wave-aggregated compaction of window candidates (keys from global)
        #pragma unroll
        for (int w = 0; w < EPT; ++w) {
            int e = t + w * NT;
            bool q = false;
            uint k = 0;
            if (e < NA) {
                k = keys[e];
                if (k != 0xFFFFFFFFu) {
                    int bin = (int)(k >> 20);
                    q = (bin >= winlo && bin < winhi);
                }
            }
            ull mask = __ballot(q);
            if (mask) {
                int leader = __ffsll(mask) - 1;
                int pbase = 0;
                if (lane == leader) pbase = atomicAdd(&s_nsel, __popcll(mask));
                pbase = __shfl(pbase, leader);
                if (q) {
                    int pos = pbase + __popcll(mask & ((1ull << lane) - 1ull));
                    if (pos < CAP) s_skey[pos] = ((ull)k << 32) | (uint)e;
                }
            }
        }
        __syncthreads();
        int nsel = s_nsel; if (nsel > CAP) nsel = CAP;

        // hybrid bitonic sort of CAP=512 ull keys ascending.
        // Element t lives in register of thread t (lane t&63); passes with
        // j<64 are intra-wave shfl_xor (no barrier); j>=64 via LDS (6 passes).
        ull k = (t < CAP) ? s_skey[t] : ~0ull;
        for (int k2 = 2; k2 <= CAP; k2 <<= 1) {
            for (int j = k2 >> 1; j > 0; j >>= 1) {
                if (j >= 64) {
                    if (t < CAP) s_skey[t] = k;
                    __syncthreads();
                    if (t < CAP) {
                        ull kp = s_skey[t ^ j];
                        bool low = (t & j) == 0;
                        bool up  = (t & k2) == 0;
                        k = ((k < kp) == (low == up)) ? k : kp;
                    }
                    __syncthreads();
                } else if (t < CAP) {
                    ull kp = __shfl_xor(k, j);
                    bool low = (t & j) == 0;
                    bool up  = (t & k2) == 0;
                    k = ((k < kp) == (low == up)) ? k : kp;
                }
            }
        }
        if (t < CAP) s_skey[t] = k;
        __syncthreads();

        // sorted walk on wave 0 (exact reference IoU + compare)
        if (t < 64) {
            int kept2 = s_kept;
            for (int cb = 0; cb < nsel && kept2 < MAXDET; cb += 64) {
                int ci = cb + lane;
                ull sk = (ci < nsel) ? s_skey[ci] : ~0ull;
                bool has = (sk != ~0ull);
                int idx = 0, lab = 0;
                float sc = 0.f, c0 = 0.f, c1 = 0.f, c2 = 0.f, c3 = 0.f, ca = 0.f;
                if (has) {
                    idx = (int)(sk & 0xFFFFFFFFull);
                    sc  = __uint_as_float(~(uint)(sk >> 32));
                    float4 rb = boxes[idx];
                    lab = labels[idx];
                    float lo = (float)lab * off;
                    c0 = rb.x + lo; c1 = rb.y + lo; c2 = rb.z + lo; c3 = rb.w + lo;
                    ca = (c2 - c0) * (c3 - c1);
                    for (int q = 0; q < kept2; ++q) {
                        float tlx = fmaxf(s_kbox[q][0], c0);
                        float tly = fmaxf(s_kbox[q][1], c1);
                        float brx = fminf(s_kbox[q][2], c2);
                        float bry = fminf(s_kbox[q][3], c3);
                        float ww = fmaxf(brx - tlx, 0.f);
                        float hh = fmaxf(bry - tly, 0.f);
                        float inter = ww * hh;
                        float iou = inter / (s_ka1[q] + ca - inter + 1e-6f);
                        if (iou > NMSTHR) { has = false; break; }
                    }
                }
                ull am = __ballot(has);
                while (am && kept2 < MAXDET) {
                    int f = __ffsll(am) - 1;
                    float f0 = __shfl(c0, f), f1 = __shfl(c1, f);
                    float f2 = __shfl(c2, f), f3 = __shfl(c3, f);
                    float fa = __shfl(ca, f);
                    int   fidx = __shfl(idx, f);
                    int   flab = __shfl(lab, f);
                    float fsc  = __shfl(sc, f);
                    if (lane == 0) {
                        s_kbox[kept2][0] = f0; s_kbox[kept2][1] = f1;
                        s_kbox[kept2][2] = f2; s_kbox[kept2][3] = f3;
                        s_ka1[kept2] = fa; s_kidx[kept2] = fidx;
                        s_kscr[kept2] = fsc; s_klab[kept2] = flab;
                    }
                    kept2++;
                    if (lane == f) has = false;
                    if (has) {
                        float tlx = fmaxf(f0, c0), tly = fmaxf(f1, c1);
                        float brx = fminf(f2, c2), bry = fminf(f3, c3);
                        float ww = fmaxf(brx - tlx, 0.f), hh = fmaxf(bry - tly, 0.f);
                        float inter = ww * hh;
                        float iou = inter / (fa + ca - inter + 1e-6f);
                        if (iou > NMSTHR) has = false;
                    }
                    am = __ballot(has);
                }
            }
            if (lane == 0) s_kept = kept2;
        }
        __syncthreads();
        if (t == 0) s_winlo = s_winhi;
    }
    __syncthreads();

    // ---- epilogue: boxes/scores/labels/valid (fp32) ----
    if (t < MAXDET) {
        int kept = s_kept;
        float4 obx = make_float4(0.f, 0.f, 0.f, 0.f);
        float osc = 0.f, olab = -1.f, oval = 0.f;
        if (t < kept) {
            int idx = s_kidx[t];
            obx  = boxes[idx];              // raw (non-offset) box
            osc  = s_kscr[t];
            olab = (float)s_klab[t];
            oval = 1.f;
        }
        float* ob = out + ((size_t)b * MAXDET + t) * 4;
        ob[0] = obx.x; ob[1] = obx.y; ob[2] = obx.z; ob[3] = obx.w;
        out[BATCH * MAXDET * 4 + b * MAXDET + t] = osc;
        out[BATCH * MAXDET * 5 + b * MAXDET + t] = olab;
        out[BATCH * MAXDET * 6 + b * MAXDET + t] = oval;
    }
}

extern "C" void kernel_launch(void* const* d_in, const int* in_sizes, int n_in,
                              void* d_out, int out_size, void* d_ws, size_t ws_size,
                              hipStream_t stream) {
    // setup_inputs() dict order: cls0, reg0, obj0, cls1, reg1, obj1, cls2, reg2, obj2
    const float* cls0 = (const float*)d_in[0];
    const float* reg0 = (const float*)d_in[1];
    const float* obj0 = (const float*)d_in[2];
    const float* cls1 = (const float*)d_in[3];
    const float* reg1 = (const float*)d_in[4];
    const float* obj1 = (const float*)d_in[5];
    const float* cls2 = (const float*)d_in[6];
    const float* reg2 = (const float*)d_in[7];
    const float* obj2 = (const float*)d_in[8];

    // ws layout: boxes | labels | keys | hist | maxabs
    char* ws = (char*)d_ws;
    size_t nBA = (size_t)BATCH * NA;
    float4* wboxes  = (float4*)ws;
    int*    wlabels = (int*)(ws + nBA * 16);
    uint*   wkeys   = (uint*)(ws + nBA * 20);
    uint*   whist   = (uint*)(ws + nBA * 24);
    uint*   wmaxabs = (uint*)(ws + nBA * 24 + (size_t)BATCH * NBINS * 4);

    // zero hist + maxabs (contiguous)
    hipMemsetAsync(whist, 0, (size_t)BATCH * NBINS * 4 + BATCH * 4, stream);

    int total = BATCH * NA;   // 268800 = 1050 * 256 exactly
    decode_kernel<<<total / 256, 256, 0, stream>>>(
        cls0, reg0, obj0, cls1, reg1, obj1, cls2, reg2, obj2,
        wboxes, wlabels, wkeys, whist, wmaxabs);

    nms_kernel<<<BATCH, NT, 0, stream>>>(wboxes, wlabels, wkeys, whist, wmaxabs,
                                         (float*)d_out);
}

// Round 8
// 184.747 us; speedup vs baseline: 1.2046x; 1.2046x over previous
//
#include <hip/hip_runtime.h>
#include <cmath>

typedef unsigned int uint;
typedef unsigned long long ull;

#define BATCH 32
#define NA 8400
#define NC 80
#define MAXDET 100
#define NMSTHR 0.65f
#define SCTHR 0.01f
#define NEG_INF (-INFINITY)

#define NT 1024         // NMS threads per block
#define NW (NT / 64)
#define EPT 9           // ceil(NA / NT)
#define NBINS 4096      // histogram bins on key[31:20]
#define CAP 512         // max candidates per sorted window

__device__ __forceinline__ float stable_sigmoid(float x) {
    if (x >= 0.f) return 1.f / (1.f + expf(-x));
    float e = expf(x);
    return e / (1.f + e);
}

// ---------------- decode: FOUR threads per anchor ----------------
// Sub-thread q scans channels [20q, 20q+20): 20 independent loads batched
// into registers (deep memory-level parallelism), then a 4-lane shfl
// butterfly merges (max, lowest-channel) -> exact jnp.argmax semantics.
template<int HW, int W, int S>
__device__ __forceinline__ void decode4(
    const float* __restrict__ cls, const float* __restrict__ reg,
    const float* __restrict__ obj, int b, int p, int q, int ag,
    float4* __restrict__ wboxes, int* __restrict__ wlabels, uint* __restrict__ wkeys)
{
    const float* cbase = cls + (size_t)b * NC * HW + (size_t)(q * 20) * HW + p;
    float v[20];
    #pragma unroll
    for (int i = 0; i < 20; ++i) v[i] = cbase[(size_t)i * HW];
    float m = v[0]; int c = 0;
    #pragma unroll
    for (int i = 1; i < 20; ++i)
        if (v[i] > m) { m = v[i]; c = i; }     // strict > -> first max in slice
    c += q * 20;

    // merge the 4 sub-threads (lanes 4k..4k+3): tie -> lower channel index
    #pragma unroll
    for (int o = 1; o <= 2; o <<= 1) {
        float om = __shfl_xor(m, o);
        int   oc = __shfl_xor(c, o);
        if (om > m || (om == m && oc < c)) { m = om; c = oc; }
    }

    if (q == 0) {
        const float* rb = reg + (size_t)b * 4 * HW + p;
        float r0 = rb[0];
        float r1 = rb[HW];
        float r2 = rb[2 * (size_t)HW];
        float r3 = rb[3 * (size_t)HW];
        float ov = obj[(size_t)b * HW + p];

        int y = p / W;            // W constexpr -> magic mul
        int x = p - y * W;
        float sc = stable_sigmoid(m) * stable_sigmoid(ov);
        float cx = r0 * (float)S + (float)x * (float)S;
        float cy = r1 * (float)S + (float)y * (float)S;
        float bw = expf(r2) * (float)S;
        float bh = expf(r3) * (float)S;

        wboxes[ag]  = make_float4(cx - bw * 0.5f, cy - bh * 0.5f,
                                  cx + bw * 0.5f, cy + bh * 0.5f);
        wlabels[ag] = c;
        wkeys[ag]   = (sc >= SCTHR) ? ~__float_as_uint(sc) : 0xFFFFFFFFu;
    }
}

__global__ __launch_bounds__(256) void decode_kernel(
    const float* __restrict__ cls0, const float* __restrict__ reg0, const float* __restrict__ obj0,
    const float* __restrict__ cls1, const float* __restrict__ reg1, const float* __restrict__ obj1,
    const float* __restrict__ cls2, const float* __restrict__ reg2, const float* __restrict__ obj2,
    float4* __restrict__ wboxes, int* __restrict__ wlabels, uint* __restrict__ wkeys)
{
    int gid = blockIdx.x * blockDim.x + threadIdx.x;   // BATCH*NA*4 threads exactly
    int ag = gid >> 2;       // global anchor id
    int q  = gid & 3;        // channel-slice id
    int b = ag / NA;
    int j = ag - b * NA;

    if (j < 6400)
        decode4<6400, 80, 8>(cls0, reg0, obj0, b, j, q, ag, wboxes, wlabels, wkeys);
    else if (j < 8000)
        decode4<1600, 40, 16>(cls1, reg1, obj1, b, j - 6400, q, ag, wboxes, wlabels, wkeys);
    else
        decode4<400, 20, 32>(cls2, reg2, obj2, b, j - 8000, q, ag, wboxes, wlabels, wkeys);
}

// ---------------- NMS via sorted walk (exact greedy-NMS equivalence) ----------------
__global__ __launch_bounds__(NT) void nms_kernel(
    const float4* __restrict__ wboxes, const int* __restrict__ wlabels,
    const uint* __restrict__ wkeys, float* __restrict__ out)
{
    int b = blockIdx.x;
    int t = threadIdx.x;
    int lane = t & 63;
    int wv = t >> 6;
    const float4* boxes  = wboxes  + (size_t)b * NA;
    const int*    labels = wlabels + (size_t)b * NA;
    const uint*   keys   = wkeys   + (size_t)b * NA;

    __shared__ uint  s_hist[NBINS];
    __shared__ uint  s_cum[NBINS + 1];    // exclusive prefix
    __shared__ uint  s_wsum[NW];
    __shared__ ull   s_skey[CAP];
    __shared__ float s_kbox[MAXDET][4];   // kept OFFSET boxes
    __shared__ float s_ka1[MAXDET];
    __shared__ int   s_kidx[MAXDET];
    __shared__ float s_kscr[MAXDET];
    __shared__ int   s_klab[MAXDET];
    __shared__ float s_red[NW];
    __shared__ float s_off;
    __shared__ int   s_kept, s_winlo, s_winhi, s_nsel;

    // ---- offset = max|coord| over ALL boxes + 1 (boxes are L2-hot) ----
    float m = 0.f;
    #pragma unroll
    for (int w = 0; w < EPT; ++w) {
        int e = t + w * NT;
        if (e < NA) {
            float4 v = boxes[e];
            m = fmaxf(m, fmaxf(fmaxf(fabsf(v.x), fabsf(v.y)),
                               fmaxf(fabsf(v.z), fabsf(v.w))));
        }
    }
    #pragma unroll
    for (int o = 32; o >= 1; o >>= 1) m = fmaxf(m, __shfl_xor(m, o));
    if (lane == 0) s_red[wv] = m;
    // ---- LDS histogram of precomputed keys ----
    for (int i = t; i < NBINS; i += NT) s_hist[i] = 0;
    if (t == 0) { s_kept = 0; s_winlo = 0; }
    __syncthreads();
    if (t == 0) {
        float mm = 0.f;
        for (int w = 0; w < NW; ++w) mm = fmaxf(mm, s_red[w]);
        s_off = mm + 1.f;
    }
    #pragma unroll
    for (int w = 0; w < EPT; ++w) {
        int e = t + w * NT;
        if (e < NA) {
            uint k = keys[e];
            if (k != 0xFFFFFFFFu) atomicAdd(&s_hist[k >> 20], 1u);
        }
    }
    __syncthreads();
    float off = s_off;

    // ---- exclusive scan over 4096 bins: 4 bins/thread + shfl scans ----
    uint l0 = s_hist[4 * t], l1 = s_hist[4 * t + 1],
         l2 = s_hist[4 * t + 2], l3 = s_hist[4 * t + 3];
    uint L = l0 + l1 + l2 + l3;
    uint ls = L;
    #pragma unroll
    for (int o = 1; o < 64; o <<= 1) {
        uint v = __shfl_up(ls, o);
        if (lane >= o) ls += v;
    }
    if (lane == 63) s_wsum[wv] = ls;
    __syncthreads();
    if (t < NW) {
        uint v = s_wsum[t];
        uint vs = v;
        #pragma unroll
        for (int o = 1; o < NW; o <<= 1) {
            uint u = __shfl_up(vs, o);
            if ((t & 63) >= o) vs += u;
        }
        s_wsum[t] = vs - v;
    }
    __syncthreads();
    uint base = s_wsum[wv] + (ls - L);
    s_cum[4 * t]     = base;
    s_cum[4 * t + 1] = base + l0;
    s_cum[4 * t + 2] = base + l0 + l1;
    s_cum[4 * t + 3] = base + l0 + l1 + l2;
    if (t == NT - 1) s_cum[NBINS] = base + L;

    // ---- window loop (typically runs once) ----
    for (;;) {
        __syncthreads();
        int kept = s_kept, winlo = s_winlo;
        uint remaining = s_cum[NBINS] - s_cum[winlo];
        if (kept >= MAXDET || winlo >= NBINS || remaining == 0u) break;
        if (t == 0) { s_winhi = winlo + 1; s_nsel = 0; }   // giant-bin clamp floor
        if (t < CAP) s_skey[t] = ~0ull;
        __syncthreads();
        // parallel winhi: predicate monotone in i -> atomicMax over qualifying i+1
        uint cl = s_cum[winlo];
        #pragma unroll
        for (int q = 0; q < 4; ++q) {
            int i = t + q * NT;
            if (i >= winlo && i < NBINS && (s_cum[i + 1] - cl) <= (uint)CAP)
                atomicMax(&s_winhi, i + 1);
        }
        __syncthreads();
        int winhi = s_winhi;

        // wave-aggregated compaction of window candidates (keys from global, L2-hot)
        #pragma unroll
        for (int w = 0; w < EPT; ++w) {
            int e = t + w * NT;
            bool q = false;
            uint k = 0;
            if (e < NA) {
                k = keys[e];
                if (k != 0xFFFFFFFFu) {
                    int bin = (int)(k >> 20);
                    q = (bin >= winlo && bin < winhi);
                }
            }
            ull mask = __ballot(q);
            if (mask) {
                int leader = __ffsll(mask) - 1;
                int pbase = 0;
                if (lane == leader) pbase = atomicAdd(&s_nsel, __popcll(mask));
                pbase = __shfl(pbase, leader);
                if (q) {
                    int pos = pbase + __popcll(mask & ((1ull << lane) - 1ull));
                    if (pos < CAP) s_skey[pos] = ((ull)k << 32) | (uint)e;
                }
            }
        }
        __syncthreads();
        int nsel = s_nsel; if (nsel > CAP) nsel = CAP;

        // hybrid bitonic sort of CAP=512 ull keys ascending: j<64 passes are
        // intra-wave shfl_xor (no barrier); j>=64 via LDS (6 barriered passes).
        ull k = (t < CAP) ? s_skey[t] : ~0ull;
        for (int k2 = 2; k2 <= CAP; k2 <<= 1) {
            for (int j = k2 >> 1; j > 0; j >>= 1) {
                if (j >= 64) {
                    if (t < CAP) s_skey[t] = k;
                    __syncthreads();
                    if (t < CAP) {
                        ull kp = s_skey[t ^ j];
                        bool low = (t & j) == 0;
                        bool up  = (t & k2) == 0;
                        k = ((k < kp) == (low == up)) ? k : kp;
                    }
                    __syncthreads();
                } else if (t < CAP) {
                    ull kp = __shfl_xor(k, j);
                    bool low = (t & j) == 0;
                    bool up  = (t & k2) == 0;
                    k = ((k < kp) == (low == up)) ? k : kp;
                }
            }
        }
        if (t < CAP) s_skey[t] = k;
        __syncthreads();

        // sorted walk on wave 0 (exact reference IoU + compare)
        if (t < 64) {
            int kept2 = s_kept;
            for (int cb = 0; cb < nsel && kept2 < MAXDET; cb += 64) {
                int ci = cb + lane;
                ull sk = (ci < nsel) ? s_skey[ci] : ~0ull;
                bool has = (sk != ~0ull);
                int idx = 0, lab = 0;
                float sc = 0.f, c0 = 0.f, c1 = 0.f, c2 = 0.f, c3 = 0.f, ca = 0.f;
                if (has) {
                    idx = (int)(sk & 0xFFFFFFFFull);
                    sc  = __uint_as_float(~(uint)(sk >> 32));   // exact score bits
                    float4 rb = boxes[idx];
                    lab = labels[idx];
                    float lo = (float)lab * off;
                    c0 = rb.x + lo; c1 = rb.y + lo; c2 = rb.z + lo; c3 = rb.w + lo;
                    ca = (c2 - c0) * (c3 - c1);
                    for (int q = 0; q < kept2; ++q) {
                        float tlx = fmaxf(s_kbox[q][0], c0);
                        float tly = fmaxf(s_kbox[q][1], c1);
                        float brx = fminf(s_kbox[q][2], c2);
                        float bry = fminf(s_kbox[q][3], c3);
                        float ww = fmaxf(brx - tlx, 0.f);
                        float hh = fmaxf(bry - tly, 0.f);
                        float inter = ww * hh;
                        float iou = inter / (s_ka1[q] + ca - inter + 1e-6f);
                        if (iou > NMSTHR) { has = false; break; }
                    }
                }
                ull am = __ballot(has);
                while (am && kept2 < MAXDET) {
                    int f = __ffsll(am) - 1;
                    float f0 = __shfl(c0, f), f1 = __shfl(c1, f);
                    float f2 = __shfl(c2, f), f3 = __shfl(c3, f);
                    float fa = __shfl(ca, f);
                    int   fidx = __shfl(idx, f);
                    int   flab = __shfl(lab, f);
                    float fsc  = __shfl(sc, f);
                    if (lane == 0) {
                        s_kbox[kept2][0] = f0; s_kbox[kept2][1] = f1;
                        s_kbox[kept2][2] = f2; s_kbox[kept2][3] = f3;
                        s_ka1[kept2] = fa; s_kidx[kept2] = fidx;
                        s_kscr[kept2] = fsc; s_klab[kept2] = flab;
                    }
                    kept2++;
                    if (lane == f) has = false;
                    if (has) {
                        float tlx = fmaxf(f0, c0), tly = fmaxf(f1, c1);
                        float brx = fminf(f2, c2), bry = fminf(f3, c3);
                        float ww = fmaxf(brx - tlx, 0.f), hh = fmaxf(bry - tly, 0.f);
                        float inter = ww * hh;
                        float iou = inter / (fa + ca - inter + 1e-6f);
                        if (iou > NMSTHR) has = false;
                    }
                    am = __ballot(has);
                }
            }
            if (lane == 0) s_kept = kept2;
        }
        __syncthreads();
        if (t == 0) s_winlo = s_winhi;
    }
    __syncthreads();

    // ---- epilogue: boxes/scores/labels/valid (fp32) ----
    if (t < MAXDET) {
        int kept = s_kept;
        float4 obx = make_float4(0.f, 0.f, 0.f, 0.f);
        float osc = 0.f, olab = -1.f, oval = 0.f;
        if (t < kept) {
            int idx = s_kidx[t];
            obx  = boxes[idx];              // raw (non-offset) box
            osc  = s_kscr[t];
            olab = (float)s_klab[t];
            oval = 1.f;
        }
        float* ob = out + ((size_t)b * MAXDET + t) * 4;
        ob[0] = obx.x; ob[1] = obx.y; ob[2] = obx.z; ob[3] = obx.w;
        out[BATCH * MAXDET * 4 + b * MAXDET + t] = osc;
        out[BATCH * MAXDET * 5 + b * MAXDET + t] = olab;
        out[BATCH * MAXDET * 6 + b * MAXDET + t] = oval;
    }
}

extern "C" void kernel_launch(void* const* d_in, const int* in_sizes, int n_in,
                              void* d_out, int out_size, void* d_ws, size_t ws_size,
                              hipStream_t stream) {
    // setup_inputs() dict order: cls0, reg0, obj0, cls1, reg1, obj1, cls2, reg2, obj2
    const float* cls0 = (const float*)d_in[0];
    const float* reg0 = (const float*)d_in[1];
    const float* obj0 = (const float*)d_in[2];
    const float* cls1 = (const float*)d_in[3];
    const float* reg1 = (const float*)d_in[4];
    const float* obj1 = (const float*)d_in[5];
    const float* cls2 = (const float*)d_in[6];
    const float* reg2 = (const float*)d_in[7];
    const float* obj2 = (const float*)d_in[8];

    // ws layout: boxes | labels | keys
    char* ws = (char*)d_ws;
    size_t nBA = (size_t)BATCH * NA;
    float4* wboxes  = (float4*)ws;
    int*    wlabels = (int*)(ws + nBA * 16);
    uint*   wkeys   = (uint*)(ws + nBA * 20);

    int total = BATCH * NA * 4;   // 1,075,200 = 4200 * 256 exactly
    decode_kernel<<<total / 256, 256, 0, stream>>>(
        cls0, reg0, obj0, cls1, reg1, obj1, cls2, reg2, obj2,
        wboxes, wlabels, wkeys);

    nms_kernel<<<BATCH, NT, 0, stream>>>(wboxes, wlabels, wkeys, (float*)d_out);
}

// Round 9
// 172.036 us; speedup vs baseline: 1.2936x; 1.0739x over previous
//
#include <hip/hip_runtime.h>
#include <cmath>

typedef unsigned int uint;
typedef unsigned long long ull;

#define BATCH 32
#define NA 8400
#define NC 80
#define MAXDET 100
#define NMSTHR 0.65f
#define SCTHR 0.01f
#define NEG_INF (-INFINITY)

#define NT 1024         // NMS threads per block
#define NW (NT / 64)
#define EPT 9           // ceil(NA / NT)
#define NBINS 4096      // histogram bins on key[31:20]
#define CAP 512         // max candidates per sorted window

__device__ __forceinline__ float stable_sigmoid(float x) {
    if (x >= 0.f) return 1.f / (1.f + expf(-x));
    float e = expf(x);
    return e / (1.f + e);
}

// ---------------- decode: FOUR threads per anchor ----------------
// Sub-thread q scans channels [20q, 20q+20): 20 independent loads batched
// into registers (deep memory-level parallelism), then a 4-lane shfl
// butterfly merges (max, lowest-channel) -> exact jnp.argmax semantics.
template<int HW, int W, int S>
__device__ __forceinline__ void decode4(
    const float* __restrict__ cls, const float* __restrict__ reg,
    const float* __restrict__ obj, int b, int p, int q, int ag,
    float4* __restrict__ wboxes, int* __restrict__ wlabels, uint* __restrict__ wkeys)
{
    const float* cbase = cls + (size_t)b * NC * HW + (size_t)(q * 20) * HW + p;
    float v[20];
    #pragma unroll
    for (int i = 0; i < 20; ++i) v[i] = cbase[(size_t)i * HW];
    float m = v[0]; int c = 0;
    #pragma unroll
    for (int i = 1; i < 20; ++i)
        if (v[i] > m) { m = v[i]; c = i; }     // strict > -> first max in slice
    c += q * 20;

    // merge the 4 sub-threads (lanes 4k..4k+3): tie -> lower channel index
    #pragma unroll
    for (int o = 1; o <= 2; o <<= 1) {
        float om = __shfl_xor(m, o);
        int   oc = __shfl_xor(c, o);
        if (om > m || (om == m && oc < c)) { m = om; c = oc; }
    }

    if (q == 0) {
        const float* rb = reg + (size_t)b * 4 * HW + p;
        float r0 = rb[0];
        float r1 = rb[HW];
        float r2 = rb[2 * (size_t)HW];
        float r3 = rb[3 * (size_t)HW];
        float ov = obj[(size_t)b * HW + p];

        int y = p / W;            // W constexpr -> magic mul
        int x = p - y * W;
        float sc = stable_sigmoid(m) * stable_sigmoid(ov);
        float cx = r0 * (float)S + (float)x * (float)S;
        float cy = r1 * (float)S + (float)y * (float)S;
        float bw = expf(r2) * (float)S;
        float bh = expf(r3) * (float)S;

        wboxes[ag]  = make_float4(cx - bw * 0.5f, cy - bh * 0.5f,
                                  cx + bw * 0.5f, cy + bh * 0.5f);
        wlabels[ag] = c;
        wkeys[ag]   = (sc >= SCTHR) ? ~__float_as_uint(sc) : 0xFFFFFFFFu;
    }
}

__global__ __launch_bounds__(256) void decode_kernel(
    const float* __restrict__ cls0, const float* __restrict__ reg0, const float* __restrict__ obj0,
    const float* __restrict__ cls1, const float* __restrict__ reg1, const float* __restrict__ obj1,
    const float* __restrict__ cls2, const float* __restrict__ reg2, const float* __restrict__ obj2,
    float4* __restrict__ wboxes, int* __restrict__ wlabels, uint* __restrict__ wkeys)
{
    int gid = blockIdx.x * blockDim.x + threadIdx.x;   // BATCH*NA*4 threads exactly
    int ag = gid >> 2;       // global anchor id
    int q  = gid & 3;        // channel-slice id
    int b = ag / NA;
    int j = ag - b * NA;

    if (j < 6400)
        decode4<6400, 80, 8>(cls0, reg0, obj0, b, j, q, ag, wboxes, wlabels, wkeys);
    else if (j < 8000)
        decode4<1600, 40, 16>(cls1, reg1, obj1, b, j - 6400, q, ag, wboxes, wlabels, wkeys);
    else
        decode4<400, 20, 32>(cls2, reg2, obj2, b, j - 8000, q, ag, wboxes, wlabels, wkeys);
}

// ---------------- NMS via sorted walk (exact greedy-NMS equivalence) ----------------
__global__ __launch_bounds__(NT) void nms_kernel(
    const float4* __restrict__ wboxes, const int* __restrict__ wlabels,
    const uint* __restrict__ wkeys, float* __restrict__ out)
{
    int b = blockIdx.x;
    int t = threadIdx.x;
    int lane = t & 63;
    int wv = t >> 6;
    const float4* boxes  = wboxes  + (size_t)b * NA;
    const int*    labels = wlabels + (size_t)b * NA;
    const uint*   keys   = wkeys   + (size_t)b * NA;

    __shared__ uint  s_hist[NBINS];
    __shared__ uint  s_cum[NBINS + 1];    // exclusive prefix
    __shared__ uint  s_wsum[NW];
    __shared__ ull   s_skey[CAP];
    __shared__ float s_kbox[MAXDET][4];   // kept OFFSET boxes
    __shared__ float s_ka1[MAXDET];
    __shared__ int   s_kidx[MAXDET];
    __shared__ float s_kscr[MAXDET];
    __shared__ int   s_klab[MAXDET];
    __shared__ float s_red[NW];
    __shared__ float s_off;
    __shared__ int   s_kept, s_winlo, s_winhi, s_nsel;

    // ---- offset = max|coord| over ALL boxes + 1 (boxes are L2/L3-hot) ----
    float m = 0.f;
    #pragma unroll
    for (int w = 0; w < EPT; ++w) {
        int e = t + w * NT;
        if (e < NA) {
            float4 v = boxes[e];
            m = fmaxf(m, fmaxf(fmaxf(fabsf(v.x), fabsf(v.y)),
                               fmaxf(fabsf(v.z), fabsf(v.w))));
        }
    }
    #pragma unroll
    for (int o = 32; o >= 1; o >>= 1) m = fmaxf(m, __shfl_xor(m, o));
    if (lane == 0) s_red[wv] = m;
    // ---- LDS histogram of precomputed keys ----
    for (int i = t; i < NBINS; i += NT) s_hist[i] = 0;
    if (t == 0) { s_kept = 0; s_winlo = 0; }
    __syncthreads();
    if (t == 0) {
        float mm = 0.f;
        for (int w = 0; w < NW; ++w) mm = fmaxf(mm, s_red[w]);
        s_off = mm + 1.f;
    }
    #pragma unroll
    for (int w = 0; w < EPT; ++w) {
        int e = t + w * NT;
        if (e < NA) {
            uint k = keys[e];
            if (k != 0xFFFFFFFFu) atomicAdd(&s_hist[k >> 20], 1u);
        }
    }
    __syncthreads();
    float off = s_off;

    // ---- exclusive scan over 4096 bins: 4 bins/thread + shfl scans ----
    uint l0 = s_hist[4 * t], l1 = s_hist[4 * t + 1],
         l2 = s_hist[4 * t + 2], l3 = s_hist[4 * t + 3];
    uint L = l0 + l1 + l2 + l3;
    uint ls = L;
    #pragma unroll
    for (int o = 1; o < 64; o <<= 1) {
        uint v = __shfl_up(ls, o);
        if (lane >= o) ls += v;
    }
    if (lane == 63) s_wsum[wv] = ls;
    __syncthreads();
    if (t < NW) {
        uint v = s_wsum[t];
        uint vs = v;
        #pragma unroll
        for (int o = 1; o < NW; o <<= 1) {
            uint u = __shfl_up(vs, o);
            if ((t & 63) >= o) vs += u;
        }
        s_wsum[t] = vs - v;
    }
    __syncthreads();
    uint base = s_wsum[wv] + (ls - L);
    s_cum[4 * t]     = base;
    s_cum[4 * t + 1] = base + l0;
    s_cum[4 * t + 2] = base + l0 + l1;
    s_cum[4 * t + 3] = base + l0 + l1 + l2;
    if (t == NT - 1) s_cum[NBINS] = base + L;

    // ---- window loop (typically runs once) ----
    for (;;) {
        __syncthreads();
        int kept = s_kept, winlo = s_winlo;
        uint remaining = s_cum[NBINS] - s_cum[winlo];
        if (kept >= MAXDET || winlo >= NBINS || remaining == 0u) break;
        if (t == 0) { s_winhi = winlo + 1; s_nsel = 0; }   // giant-bin clamp floor
        if (t < CAP) s_skey[t] = ~0ull;
        __syncthreads();
        // winhi via unique-boundary store: pred(i) = cum[i+1]-cl <= CAP is
        // monotone non-increasing in i, so exactly one i has pred(i) && !pred(i+1).
        // (Round 6-8 used atomicMax over ~3000 qualifying empty bins -> ~3000
        //  serialized same-address LDS atomics ~= 45 us/launch. This is the fix.)
        uint cl = s_cum[winlo];
        #pragma unroll
        for (int q = 0; q < 4; ++q) {
            int i = t + q * NT;
            if (i >= winlo && i < NBINS) {
                bool p0 = (s_cum[i + 1] - cl) <= (uint)CAP;
                bool p1 = (i + 1 < NBINS) && ((s_cum[i + 2] - cl) <= (uint)CAP);
                if (p0 && !p1) s_winhi = i + 1;   // unique writer
            }
        }
        __syncthreads();
        int winhi = s_winhi;

        // wave-aggregated compaction of window candidates (keys from global, L2-hot)
        #pragma unroll
        for (int w = 0; w < EPT; ++w) {
            int e = t + w * NT;
            bool q = false;
            uint k = 0;
            if (e < NA) {
                k = keys[e];
                if (k != 0xFFFFFFFFu) {
                    int bin = (int)(k >> 20);
                    q = (bin >= winlo && bin < winhi);
                }
            }
            ull mask = __ballot(q);
            if (mask) {
                int leader = __ffsll(mask) - 1;
                int pbase = 0;
                if (lane == leader) pbase = atomicAdd(&s_nsel, __popcll(mask));
                pbase = __shfl(pbase, leader);
                if (q) {
                    int pos = pbase + __popcll(mask & ((1ull << lane) - 1ull));
                    if (pos < CAP) s_skey[pos] = ((ull)k << 32) | (uint)e;
                }
            }
        }
        __syncthreads();
        int nsel = s_nsel; if (nsel > CAP) nsel = CAP;

        // hybrid bitonic sort of CAP=512 ull keys ascending: j<64 passes are
        // intra-wave shfl_xor (no barrier); j>=64 via LDS (6 barriered passes).
        ull k = (t < CAP) ? s_skey[t] : ~0ull;
        for (int k2 = 2; k2 <= CAP; k2 <<= 1) {
            for (int j = k2 >> 1; j > 0; j >>= 1) {
                if (j >= 64) {
                    if (t < CAP) s_skey[t] = k;
                    __syncthreads();
                    if (t < CAP) {
                        ull kp = s_skey[t ^ j];
                        bool low = (t & j) == 0;
                        bool up  = (t & k2) == 0;
                        k = ((k < kp) == (low == up)) ? k : kp;
                    }
                    __syncthreads();
                } else if (t < CAP) {
                    ull kp = __shfl_xor(k, j);
                    bool low = (t & j) == 0;
                    bool up  = (t & k2) == 0;
                    k = ((k < kp) == (low == up)) ? k : kp;
                }
            }
        }
        if (t < CAP) s_skey[t] = k;
        __syncthreads();

        // sorted walk on wave 0 (exact reference IoU + compare)
        if (t < 64) {
            int kept2 = s_kept;
            for (int cb = 0; cb < nsel && kept2 < MAXDET; cb += 64) {
                int ci = cb + lane;
                ull sk = (ci < nsel) ? s_skey[ci] : ~0ull;
                bool has = (sk != ~0ull);
                int idx = 0, lab = 0;
                float sc = 0.f, c0 = 0.f, c1 = 0.f, c2 = 0.f, c3 = 0.f, ca = 0.f;
                if (has) {
                    idx = (int)(sk & 0xFFFFFFFFull);
                    sc  = __uint_as_float(~(uint)(sk >> 32));   // exact score bits
                    float4 rb = boxes[idx];
                    lab = labels[idx];
                    float lo = (float)lab * off;
                    c0 = rb.x + lo; c1 = rb.y + lo; c2 = rb.z + lo; c3 = rb.w + lo;
                    ca = (c2 - c0) * (c3 - c1);
                    for (int q = 0; q < kept2; ++q) {
                        float tlx = fmaxf(s_kbox[q][0], c0);
                        float tly = fmaxf(s_kbox[q][1], c1);
                        float brx = fminf(s_kbox[q][2], c2);
                        float bry = fminf(s_kbox[q][3], c3);
                        float ww = fmaxf(brx - tlx, 0.f);
                        float hh = fmaxf(bry - tly, 0.f);
                        float inter = ww * hh;
                        float iou = inter / (s_ka1[q] + ca - inter + 1e-6f);
                        if (iou > NMSTHR) { has = false; break; }
                    }
                }
                ull am = __ballot(has);
                while (am && kept2 < MAXDET) {
                    int f = __ffsll(am) - 1;
                    float f0 = __shfl(c0, f), f1 = __shfl(c1, f);
                    float f2 = __shfl(c2, f), f3 = __shfl(c3, f);
                    float fa = __shfl(ca, f);
                    int   fidx = __shfl(idx, f);
                    int   flab = __shfl(lab, f);
                    float fsc  = __shfl(sc, f);
                    if (lane == 0) {
                        s_kbox[kept2][0] = f0; s_kbox[kept2][1] = f1;
                        s_kbox[kept2][2] = f2; s_kbox[kept2][3] = f3;
                        s_ka1[kept2] = fa; s_kidx[kept2] = fidx;
                        s_kscr[kept2] = fsc; s_klab[kept2] = flab;
                    }
                    kept2++;
                    if (lane == f) has = false;
                    if (has) {
                        float tlx = fmaxf(f0, c0), tly = fmaxf(f1, c1);
                        float brx = fminf(f2, c2), bry = fminf(f3, c3);
                        float ww = fmaxf(brx - tlx, 0.f), hh = fmaxf(bry - tly, 0.f);
                        float inter = ww * hh;
                        float iou = inter / (fa + ca - inter + 1e-6f);
                        if (iou > NMSTHR) has = false;
                    }
                    am = __ballot(has);
                }
            }
            if (lane == 0) s_kept = kept2;
        }
        __syncthreads();
        if (t == 0) s_winlo = s_winhi;
    }
    __syncthreads();

    // ---- epilogue: boxes/scores/labels/valid (fp32) ----
    if (t < MAXDET) {
        int kept = s_kept;
        float4 obx = make_float4(0.f, 0.f, 0.f, 0.f);
        float osc = 0.f, olab = -1.f, oval = 0.f;
        if (t < kept) {
            int idx = s_kidx[t];
            obx  = boxes[idx];              // raw (non-offset) box
            osc  = s_kscr[t];
            olab = (float)s_klab[t];
            oval = 1.f;
        }
        float* ob = out + ((size_t)b * MAXDET + t) * 4;
        ob[0] = obx.x; ob[1] = obx.y; ob[2] = obx.z; ob[3] = obx.w;
        out[BATCH * MAXDET * 4 + b * MAXDET + t] = osc;
        out[BATCH * MAXDET * 5 + b * MAXDET + t] = olab;
        out[BATCH * MAXDET * 6 + b * MAXDET + t] = oval;
    }
}

extern "C" void kernel_launch(void* const* d_in, const int* in_sizes, int n_in,
                              void* d_out, int out_size, void* d_ws, size_t ws_size,
                              hipStream_t stream) {
    // setup_inputs() dict order: cls0, reg0, obj0, cls1, reg1, obj1, cls2, reg2, obj2
    const float* cls0 = (const float*)d_in[0];
    const float* reg0 = (const float*)d_in[1];
    const float* obj0 = (const float*)d_in[2];
    const float* cls1 = (const float*)d_in[3];
    const float* reg1 = (const float*)d_in[4];
    const float* obj1 = (const float*)d_in[5];
    const float* cls2 = (const float*)d_in[6];
    const float* reg2 = (const float*)d_in[7];
    const float* obj2 = (const float*)d_in[8];

    // ws layout: boxes | labels | keys
    char* ws = (char*)d_ws;
    size_t nBA = (size_t)BATCH * NA;
    float4* wboxes  = (float4*)ws;
    int*    wlabels = (int*)(ws + nBA * 16);
    uint*   wkeys   = (uint*)(ws + nBA * 20);

    int total = BATCH * NA * 4;   // 1,075,200 = 4200 * 256 exactly
    decode_kernel<<<total / 256, 256, 0, stream>>>(
        cls0, reg0, obj0, cls1, reg1, obj1, cls2, reg2, obj2,
        wboxes, wlabels, wkeys);

    nms_kernel<<<BATCH, NT, 0, stream>>>(wboxes, wlabels, wkeys, (float*)d_out);
}